// Round 1
// baseline (94.538 us; speedup 1.0000x reference)
//
#include <hip/hip_runtime.h>

#define BATCH 32
#define T_LEN 4096
#define VOCAB 1025
#define BLANK 1024

// One 64-lane wave per (b,t) row: argmax over 1025 floats with
// lowest-index tie-break (jnp.argmax semantics).
__global__ __launch_bounds__(256) void ctc_argmax_kernel(
    const float* __restrict__ lp,
    float* __restrict__ preds,
    float* __restrict__ maxlp)
{
    const int gtid = blockIdx.x * blockDim.x + threadIdx.x;
    const int row  = gtid >> 6;            // one wave per row
    const int lane = threadIdx.x & 63;
    if (row >= BATCH * T_LEN) return;

    const float* rp = lp + (long long)row * VOCAB;

    float best = -3.402823e38f;
    int   bidx = 0x7fffffff;

    // 16 full strided passes: idx = lane + k*64, coalesced 256B/wave/iter.
    // Within a lane indices only increase, so strict '>' keeps the first
    // occurrence of the max (lowest index).
    #pragma unroll
    for (int k = 0; k < 16; ++k) {
        const int idx = lane + (k << 6);
        const float v = rp[idx];
        if (v > best) { best = v; bidx = idx; }
    }
    // tail element 1024 (only lane 0)
    if (lane == 0) {
        const float v = rp[1024];
        if (v > best) { best = v; bidx = 1024; }
    }

    // 64-lane butterfly reduce; tie-break to smaller index.
    #pragma unroll
    for (int off = 32; off; off >>= 1) {
        const float ov = __shfl_xor(best, off, 64);
        const int   oi = __shfl_xor(bidx, off, 64);
        if (ov > best || (ov == best && oi < bidx)) { best = ov; bidx = oi; }
    }

    if (lane == 0) {
        preds[row] = (float)bidx;
        maxlp[row] = best;
    }
}

// Elementwise CTC collapse mask. Reads preds (as floats) written by kernel 1.
// Detects whether input_lengths arrived as int64 (reference dtype) or int32
// (harness int convention) using only the first 128 bytes of the buffer.
__global__ __launch_bounds__(256) void ctc_keep_kernel(
    const float* __restrict__ preds,
    const void* __restrict__ len_raw,
    float* __restrict__ keep)
{
    const int b = blockIdx.y;
    const int t = blockIdx.x * blockDim.x + threadIdx.x;
    if (t >= T_LEN) return;

    const long long* p64 = (const long long*)len_raw;
    const int*       p32 = (const int*)len_raw;

    // If data is int32, p64[i] combines two lengths (each >=1) -> high word
    // nonzero -> value > T_LEN. If int64, all in [1, T_LEN]. First 16 int64
    // slots = 128 B, within the buffer for either dtype (32*4B=128B min).
    bool is64 = true;
    #pragma unroll
    for (int i = 0; i < 16; ++i) {
        const long long v = p64[i];
        if (v < 1 || v > (long long)T_LEN) is64 = false;
    }
    const long long len = is64 ? p64[b] : (long long)p32[b];

    const int p    = (int)preds[b * T_LEN + t];
    const int prev = (t == 0) ? -1 : (int)preds[b * T_LEN + t - 1];

    const bool k = (p != BLANK) && (p != prev) && ((long long)t < len);
    keep[b * T_LEN + t] = k ? 1.0f : 0.0f;
}

extern "C" void kernel_launch(void* const* d_in, const int* in_sizes, int n_in,
                              void* d_out, int out_size, void* d_ws, size_t ws_size,
                              hipStream_t stream)
{
    const float* lp   = (const float*)d_in[0];
    const void*  lens = (const void*)d_in[1];

    float* out    = (float*)d_out;
    float* preds  = out;                         // [B*T]
    float* keepm  = out + BATCH * T_LEN;         // [B*T]
    float* maxlp  = out + 2 * BATCH * T_LEN;     // [B*T]

    // Kernel 1: one wave per row; 4 waves per 256-thread block.
    const int rows   = BATCH * T_LEN;
    const int blocks = rows / 4;                 // 131072/4 = 32768
    ctc_argmax_kernel<<<blocks, 256, 0, stream>>>(lp, preds, maxlp);

    // Kernel 2: [T/256, B] grid of 256-thread blocks.
    dim3 grid2(T_LEN / 256, BATCH);
    ctc_keep_kernel<<<grid2, 256, 0, stream>>>(preds, lens, keepm);
}

// Round 3
// 89.307 us; speedup vs baseline: 1.0586x; 1.0586x over previous
//
#include <hip/hip_runtime.h>

#define BATCH 32
#define T_LEN 4096
#define VOCAB 1025
#define BLANK 1024
#define NEG_INF (-3.402823466e38f)

typedef float f32x4 __attribute__((ext_vector_type(4)));

// One 64-lane wave per (b,t) row: argmax over 1025 floats with
// lowest-index tie-break (jnp.argmax semantics). Vectorized:
// align row window down to 16B, 4 passes of float4, scalar tail.
__global__ __launch_bounds__(256) void ctc_argmax_kernel(
    const float* __restrict__ lp,
    float* __restrict__ preds,
    float* __restrict__ maxlp)
{
    const int gtid = blockIdx.x * blockDim.x + threadIdx.x;
    const int row  = gtid >> 6;            // one wave per row
    const int lane = threadIdx.x & 63;
    if (row >= BATCH * T_LEN) return;

    const long long rowStartF = (long long)row * VOCAB;   // float index of row start
    const long long a0        = rowStartF & ~3LL;         // 16B-aligned float index
    const int       off       = (int)(rowStartF & 3LL);   // 0..3 leading pad floats

    const f32x4* __restrict__ p4 = (const f32x4*)(lp + a0);
    const float* __restrict__ rp = lp + rowStartF;

    float best = NEG_INF;
    int   bidx = 0x7fffffff;

    // 4 vector passes: float4 #(lane + 64k). Row-relative element index
    // idx = 4*(lane+64k) + j - off, covering idx in [-off, 1023-off].
    #pragma unroll
    for (int k = 0; k < 4; ++k) {
        f32x4 v = __builtin_nontemporal_load(&p4[lane + (k << 6)]);
        if (k == 0 && lane == 0) {
            // leading pad elements (j < off) belong to the previous row
            if (off > 0) v.x = NEG_INF;
            if (off > 1) v.y = NEG_INF;
            if (off > 2) v.z = NEG_INF;
        }
        const int base = 4 * (lane + (k << 6)) - off;
        if (v.x > best) { best = v.x; bidx = base + 0; }
        if (v.y > best) { best = v.y; bidx = base + 1; }
        if (v.z > best) { best = v.z; bidx = base + 2; }
        if (v.w > best) { best = v.w; bidx = base + 3; }
    }
    // scalar tail: indices 1024-off .. 1024 (off+1 elements), all in-row.
    if (lane <= off) {
        const int idx = 1024 - off + lane;
        const float v = rp[idx];
        if (v > best) { best = v; bidx = idx; }
    }

    // 64-lane butterfly reduce; tie-break to smaller index.
    #pragma unroll
    for (int o = 32; o; o >>= 1) {
        const float ov = __shfl_xor(best, o, 64);
        const int   oi = __shfl_xor(bidx, o, 64);
        if (ov > best || (ov == best && oi < bidx)) { best = ov; bidx = oi; }
    }

    if (lane == 0) {
        preds[row] = (float)bidx;
        maxlp[row] = best;
    }
}

// Elementwise CTC collapse mask. Reads preds (as floats) written by kernel 1.
// Detects whether input_lengths arrived as int64 (reference dtype) or int32
// (harness int convention) using only the first 128 bytes of the buffer.
__global__ __launch_bounds__(256) void ctc_keep_kernel(
    const float* __restrict__ preds,
    const void* __restrict__ len_raw,
    float* __restrict__ keep)
{
    const int b = blockIdx.y;
    const int t = blockIdx.x * blockDim.x + threadIdx.x;
    if (t >= T_LEN) return;

    const long long* p64 = (const long long*)len_raw;
    const int*       p32 = (const int*)len_raw;

    bool is64 = true;
    #pragma unroll
    for (int i = 0; i < 16; ++i) {
        const long long v = p64[i];
        if (v < 1 || v > (long long)T_LEN) is64 = false;
    }
    const long long len = is64 ? p64[b] : (long long)p32[b];

    const int p    = (int)preds[b * T_LEN + t];
    const int prev = (t == 0) ? -1 : (int)preds[b * T_LEN + t - 1];

    const bool k = (p != BLANK) && (p != prev) && ((long long)t < len);
    keep[b * T_LEN + t] = k ? 1.0f : 0.0f;
}

extern "C" void kernel_launch(void* const* d_in, const int* in_sizes, int n_in,
                              void* d_out, int out_size, void* d_ws, size_t ws_size,
                              hipStream_t stream)
{
    const float* lp   = (const float*)d_in[0];
    const void*  lens = (const void*)d_in[1];

    float* out    = (float*)d_out;
    float* preds  = out;                         // [B*T]
    float* keepm  = out + BATCH * T_LEN;         // [B*T]
    float* maxlp  = out + 2 * BATCH * T_LEN;     // [B*T]

    // Kernel 1: one wave per row; 4 waves per 256-thread block.
    const int rows   = BATCH * T_LEN;
    const int blocks = rows / 4;                 // 131072/4 = 32768
    ctc_argmax_kernel<<<blocks, 256, 0, stream>>>(lp, preds, maxlp);

    // Kernel 2: [T/256, B] grid of 256-thread blocks.
    dim3 grid2(T_LEN / 256, BATCH);
    ctc_keep_kernel<<<grid2, 256, 0, stream>>>(preds, lens, keepm);
}